// Round 2
// baseline (147.219 us; speedup 1.0000x reference)
//
#include <hip/hip_runtime.h>

#define NIN 256
#define G 16
#define U 16
#define F 32
#define LEVELS 4
#define ROWS 16
#define COLS 1024

__device__ __forceinline__ float fast_tanh(float x) {
    // tanh(x) = 1 - 2/(exp(2x)+1); exp(2x) = exp2(x * 2*log2(e))
    float e = __builtin_amdgcn_exp2f(x * 2.8853900817779268f);
    return 1.0f - 2.0f * __builtin_amdgcn_rcpf(e + 1.0f);
}

// Transposed + bank-swizzled LDS layout:
//   value (row, col) lives at byte  (col<<6) | (slot<<4) | ((row&3)<<2)
//   with slot = (row>>2) ^ ((col>>2)&3)   (XOR bijective in wave -> race-free)
// One ds_read_b128 at a column fetches the wave's 4 rows at once.

extern "C" __global__ __launch_bounds__(256, 2)
void denc_kernel(const float* __restrict__ x,
                 const float* __restrict__ k1, const float* __restrict__ b1, const int* __restrict__ i1,
                 const float* __restrict__ k2, const float* __restrict__ b2, const int* __restrict__ i2,
                 const float* __restrict__ k3, const float* __restrict__ b3, const int* __restrict__ i3,
                 const float* __restrict__ k4, const float* __restrict__ b4, const int* __restrict__ i4,
                 float* __restrict__ out)
{
    __shared__ float flat[ROWS * COLS];          // 64 KiB, transposed+swizzled
    char* const lds = (char*)flat;

    const int tid   = threadIdx.x;
    const int w     = tid >> 6;                  // wave 0..3 owns rows 4w..4w+3
    const int lane  = tid & 63;
    const int g     = lane >> 2;                 // group 0..15
    const int qq    = lane & 3;                  // u-quad 0..3
    const int r0    = blockIdx.x * ROWS;
    const int wbits = w << 4;

    // byte offset of (col, this wave's row-quad); XOR-separable swizzle
    auto coff = [&](int col) -> int {
        return ((col << 6) | ((col & 12) << 2)) ^ wbits;
    };

    // ---- stage x transposed: wave w writes its own rows 4w..4w+3 ----
    {
        const float* xb = x + ((size_t)(r0 + 4 * w)) * NIN;
        #pragma unroll
        for (int i = 0; i < 4; ++i) {
            const int col = i * 64 + lane;       // coalesced 256B per row-read
            float4 v;
            v.x = xb[col];
            v.y = xb[NIN + col];
            v.z = xb[2 * NIN + col];
            v.w = xb[3 * NIN + col];
            *(float4*)(lds + coff(col)) = v;     // ds_write_b128
        }
    }
    // No __syncthreads anywhere: each wave reads/writes only its own 16B slots.

    const float* Ks[LEVELS] = {k1, k2, k3, k4};
    const float* Bs[LEVELS] = {b1, b2, b3, b4};
    const int*   Is[LEVELS] = {i1, i2, i3, i4};

    const int po = g & 1;                        // write-order permutation

    #pragma unroll
    for (int l = 0; l < LEVELS; ++l) {
        const float4* Kp4 = (const float4*)Ks[l];
        const int4*   Ip4 = (const int4*)Is[l];

        // gather byte-offsets, swizzled once per (level, f)
        int off[F];
        #pragma unroll
        for (int j = 0; j < 8; ++j) {
            const int4 ii = Ip4[g * 8 + j];
            off[4 * j + 0] = coff(ii.x);
            off[4 * j + 1] = coff(ii.y);
            off[4 * j + 2] = coff(ii.z);
            off[4 * j + 3] = coff(ii.w);
        }

        const float4 bv = ((const float4*)Bs[l])[g * 4 + qq];
        float4 A0 = bv, A1 = bv, A2 = bv, A3 = bv;   // rows 4w+0..3, u-quad each

        #pragma unroll                                 // FULL unroll: off[] stays in VGPRs
        for (int f = 0; f < F; ++f) {
            const float4 s  = *(const float4*)(lds + off[f]);   // 4 rows, 1 ds_read_b128
            const float4 kf = Kp4[(g * F + f) * 4 + qq];        // K[g][f][4qq..4qq+3]
            A0.x = fmaf(s.x, kf.x, A0.x); A0.y = fmaf(s.x, kf.y, A0.y);
            A0.z = fmaf(s.x, kf.z, A0.z); A0.w = fmaf(s.x, kf.w, A0.w);
            A1.x = fmaf(s.y, kf.x, A1.x); A1.y = fmaf(s.y, kf.y, A1.y);
            A1.z = fmaf(s.y, kf.z, A1.z); A1.w = fmaf(s.y, kf.w, A1.w);
            A2.x = fmaf(s.z, kf.x, A2.x); A2.y = fmaf(s.z, kf.y, A2.y);
            A2.z = fmaf(s.z, kf.z, A2.z); A2.w = fmaf(s.z, kf.w, A2.w);
            A3.x = fmaf(s.w, kf.x, A3.x); A3.y = fmaf(s.w, kf.y, A3.y);
            A3.z = fmaf(s.w, kf.z, A3.z); A3.w = fmaf(s.w, kf.w, A3.w);
        }

        A0.x = fast_tanh(A0.x); A0.y = fast_tanh(A0.y); A0.z = fast_tanh(A0.z); A0.w = fast_tanh(A0.w);
        A1.x = fast_tanh(A1.x); A1.y = fast_tanh(A1.y); A1.z = fast_tanh(A1.z); A1.w = fast_tanh(A1.w);
        A2.x = fast_tanh(A2.x); A2.y = fast_tanh(A2.y); A2.z = fast_tanh(A2.z); A2.w = fast_tanh(A2.w);
        A3.x = fast_tanh(A3.x); A3.y = fast_tanh(A3.y); A3.z = fast_tanh(A3.z); A3.w = fast_tanh(A3.w);

        if (l < LEVELS - 1) {
            // write back transposed: col obase+c holds (A0[c],A1[c],A2[c],A3[c])
            const int obase = NIN + l * (G * U) + g * U + qq * 4;
            const float4 Wx = make_float4(A0.x, A1.x, A2.x, A3.x);
            const float4 Wy = make_float4(A0.y, A1.y, A2.y, A3.y);
            const float4 Wz = make_float4(A0.z, A1.z, A2.z, A3.z);
            const float4 Ww = make_float4(A0.w, A1.w, A2.w, A3.w);
            // uu ^ (g&1) write order spreads bank-quads 16-way -> 8-way-uniform
            *(float4*)(lds + coff(obase + (0 ^ po))) = po ? Wy : Wx;
            *(float4*)(lds + coff(obase + (1 ^ po))) = po ? Wx : Wy;
            *(float4*)(lds + coff(obase + (2 ^ po))) = po ? Ww : Wz;
            *(float4*)(lds + coff(obase + (3 ^ po))) = po ? Wz : Ww;
        } else {
            // final level: rows are contiguous in out -> coalesced dwordx4
            float4* ob = (float4*)(out + ((size_t)(r0 + 4 * w)) * (G * U));
            const int c4 = g * 4 + qq;           // 64 float4 per output row
            ob[c4]       = A0;
            ob[64 + c4]  = A1;
            ob[128 + c4] = A2;
            ob[192 + c4] = A3;
        }
    }
}

extern "C" void kernel_launch(void* const* d_in, const int* in_sizes, int n_in,
                              void* d_out, int out_size, void* d_ws, size_t ws_size,
                              hipStream_t stream) {
    const float* x  = (const float*)d_in[0];
    const float* k1 = (const float*)d_in[1];
    const float* b1 = (const float*)d_in[2];
    const int*   i1 = (const int*)  d_in[3];
    const float* k2 = (const float*)d_in[4];
    const float* b2 = (const float*)d_in[5];
    const int*   i2 = (const int*)  d_in[6];
    const float* k3 = (const float*)d_in[7];
    const float* b3 = (const float*)d_in[8];
    const int*   i3 = (const int*)  d_in[9];
    const float* k4 = (const float*)d_in[10];
    const float* b4 = (const float*)d_in[11];
    const int*   i4 = (const int*)  d_in[12];
    float* out = (float*)d_out;

    const int batch = in_sizes[0] / NIN;      // 65536
    dim3 grid(batch / ROWS);                  // 4096 blocks
    dim3 block(256);
    hipLaunchKernelGGL(denc_kernel, grid, block, 0, stream,
                       x, k1, b1, i1, k2, b2, i2, k3, b3, i3, k4, b4, i4, out);
}

// Round 3
// 131.348 us; speedup vs baseline: 1.1208x; 1.1208x over previous
//
#include <hip/hip_runtime.h>

#define NIN 256
#define G 16
#define U 16
#define F 32
#define LEVELS 4
#define ROWS 16
#define COLS 1024

typedef float f32x2 __attribute__((ext_vector_type(2)));

__device__ __forceinline__ float fast_tanh(float x) {
    // tanh(x) = 1 - 2/(exp(2x)+1); exp(2x) = exp2(x * 2*log2(e))
    float e = __builtin_amdgcn_exp2f(x * 2.8853900817779268f);
    return 1.0f - 2.0f * __builtin_amdgcn_rcpf(e + 1.0f);
}

__device__ __forceinline__ void pkfma(f32x2& a, float s, f32x2 k) {
#if __has_builtin(__builtin_elementwise_fma)
    f32x2 sv = {s, s};
    a = __builtin_elementwise_fma(sv, k, a);           // -> v_pk_fma_f32
#else
    a.x = fmaf(s, k.x, a.x);
    a.y = fmaf(s, k.y, a.y);
#endif
}

// Transposed + bank-swizzled LDS layout (same as R2, which validated):
//   value (row, col) at byte  (col<<6) | (slot<<4) | ((row&3)<<2),
//   slot = (row>>2) ^ ((col>>2)&3).  One ds_read_b128 = wave's 4 rows of a col.

extern "C" __global__ __launch_bounds__(256, 3)
void denc_kernel(const float* __restrict__ x,
                 const float* __restrict__ k1, const float* __restrict__ b1, const int* __restrict__ i1,
                 const float* __restrict__ k2, const float* __restrict__ b2, const int* __restrict__ i2,
                 const float* __restrict__ k3, const float* __restrict__ b3, const int* __restrict__ i3,
                 const float* __restrict__ k4, const float* __restrict__ b4, const int* __restrict__ i4,
                 float* __restrict__ out)
{
    __shared__ float flat[ROWS * COLS];          // 64 KiB, transposed+swizzled
    char* const lds = (char*)flat;

    const int tid   = threadIdx.x;
    const int w     = tid >> 6;                  // wave 0..3 owns rows 4w..4w+3
    const int lane  = tid & 63;
    const int g     = lane >> 2;                 // group 0..15
    const int qq    = lane & 3;                  // u-quad 0..3
    const int r0    = blockIdx.x * ROWS;
    const int wbits = w << 4;

    auto coff = [&](int col) -> int {
        return ((col << 6) | ((col & 12) << 2)) ^ wbits;
    };

    // ---- stage x transposed: wave w writes only its own rows (no barriers) ----
    {
        const float* xb = x + ((size_t)(r0 + 4 * w)) * NIN;
        #pragma unroll
        for (int i = 0; i < 4; ++i) {
            const int col = i * 64 + lane;
            float4 v;
            v.x = xb[col];
            v.y = xb[NIN + col];
            v.z = xb[2 * NIN + col];
            v.w = xb[3 * NIN + col];
            *(float4*)(lds + coff(col)) = v;     // ds_write_b128
        }
    }

    const float* Ks[LEVELS] = {k1, k2, k3, k4};
    const float* Bs[LEVELS] = {b1, b2, b3, b4};
    const int*   Is[LEVELS] = {i1, i2, i3, i4};

    const int po = g & 1;                        // write-order permutation

#define FMABLK(sv, kv) do {                                      \
        const f32x2 klo = {kv.x, kv.y}, khi = {kv.z, kv.w};      \
        pkfma(a0l, sv.x, klo); pkfma(a0h, sv.x, khi);            \
        pkfma(a1l, sv.y, klo); pkfma(a1h, sv.y, khi);            \
        pkfma(a2l, sv.z, klo); pkfma(a2h, sv.z, khi);            \
        pkfma(a3l, sv.w, klo); pkfma(a3h, sv.w, khi);            \
    } while (0)

    #pragma unroll
    for (int l = 0; l < LEVELS; ++l) {
        // per-thread K base: element f at Kb[f*4] (byte offset f*64 -> imm-foldable)
        const float4* Kb  = (const float4*)Ks[l] + (size_t)(g * F) * 4 + qq;
        const int4*   Ip4 = (const int4*)Is[l];

        const float4 bv = ((const float4*)Bs[l])[g * 4 + qq];
        f32x2 a0l = {bv.x, bv.y}, a0h = {bv.z, bv.w};
        f32x2 a1l = a0l, a1h = a0h;
        f32x2 a2l = a0l, a2h = a0h;
        f32x2 a3l = a0l, a3h = a0h;

        int4 nidx = Ip4[g * 8];                  // prologue idx prefetch
        #pragma unroll
        for (int j = 0; j < 8; ++j) {
            const int4 ii = nidx;
            if (j < 7) nidx = Ip4[g * 8 + j + 1];   // prefetch next chunk's idx
            const int o0 = coff(ii.x), o1 = coff(ii.y);
            const int o2 = coff(ii.z), o3 = coff(ii.w);
            const float4 s0 = *(const float4*)(lds + o0);   // 4 rows / read
            const float4 s1 = *(const float4*)(lds + o1);
            const float4 s2 = *(const float4*)(lds + o2);
            const float4 s3 = *(const float4*)(lds + o3);
            const float4 kA = Kb[(4 * j + 0) * 4];
            const float4 kB_ = Kb[(4 * j + 1) * 4];
            const float4 kC = Kb[(4 * j + 2) * 4];
            const float4 kD = Kb[(4 * j + 3) * 4];
            FMABLK(s0, kA);
            FMABLK(s1, kB_);
            FMABLK(s2, kC);
            FMABLK(s3, kD);
        }

        const float4 A0 = make_float4(fast_tanh(a0l.x), fast_tanh(a0l.y), fast_tanh(a0h.x), fast_tanh(a0h.y));
        const float4 A1 = make_float4(fast_tanh(a1l.x), fast_tanh(a1l.y), fast_tanh(a1h.x), fast_tanh(a1h.y));
        const float4 A2 = make_float4(fast_tanh(a2l.x), fast_tanh(a2l.y), fast_tanh(a2h.x), fast_tanh(a2h.y));
        const float4 A3 = make_float4(fast_tanh(a3l.x), fast_tanh(a3l.y), fast_tanh(a3h.x), fast_tanh(a3h.y));

        if (l < LEVELS - 1) {
            const int obase = NIN + l * (G * U) + g * U + qq * 4;
            const float4 Wx = make_float4(A0.x, A1.x, A2.x, A3.x);
            const float4 Wy = make_float4(A0.y, A1.y, A2.y, A3.y);
            const float4 Wz = make_float4(A0.z, A1.z, A2.z, A3.z);
            const float4 Ww = make_float4(A0.w, A1.w, A2.w, A3.w);
            *(float4*)(lds + coff(obase + (0 ^ po))) = po ? Wy : Wx;
            *(float4*)(lds + coff(obase + (1 ^ po))) = po ? Wx : Wy;
            *(float4*)(lds + coff(obase + (2 ^ po))) = po ? Ww : Wz;
            *(float4*)(lds + coff(obase + (3 ^ po))) = po ? Wz : Ww;
        } else {
            float4* ob = (float4*)(out + ((size_t)(r0 + 4 * w)) * (G * U));
            const int c4 = g * 4 + qq;
            ob[c4]       = A0;
            ob[64 + c4]  = A1;
            ob[128 + c4] = A2;
            ob[192 + c4] = A3;
        }
    }
#undef FMABLK
}

extern "C" void kernel_launch(void* const* d_in, const int* in_sizes, int n_in,
                              void* d_out, int out_size, void* d_ws, size_t ws_size,
                              hipStream_t stream) {
    const float* x  = (const float*)d_in[0];
    const float* k1 = (const float*)d_in[1];
    const float* b1 = (const float*)d_in[2];
    const int*   i1 = (const int*)  d_in[3];
    const float* k2 = (const float*)d_in[4];
    const float* b2 = (const float*)d_in[5];
    const int*   i2 = (const int*)  d_in[6];
    const float* k3 = (const float*)d_in[7];
    const float* b3 = (const float*)d_in[8];
    const int*   i3 = (const int*)  d_in[9];
    const float* k4 = (const float*)d_in[10];
    const float* b4 = (const float*)d_in[11];
    const int*   i4 = (const int*)  d_in[12];
    float* out = (float*)d_out;

    const int batch = in_sizes[0] / NIN;      // 65536
    dim3 grid(batch / ROWS);                  // 4096 blocks
    dim3 block(256);
    hipLaunchKernelGGL(denc_kernel, grid, block, 0, stream,
                       x, k1, b1, i1, k2, b2, i2, k3, b3, i3, k4, b4, i4, out);
}

// Round 5
// 85.139 us; speedup vs baseline: 1.7292x; 1.5427x over previous
//
#include <hip/hip_runtime.h>

#define NIN 256
#define G 16
#define U 16
#define F 32
#define RPB 32              // rows per block: 4 waves x 8 rows
#define TILE_I4 4096        // 1024 cols x 4 wave-slots x 16B = 64 KiB

typedef float  f32x2 __attribute__((ext_vector_type(2)));
typedef __fp16 f16x2 __attribute__((ext_vector_type(2)));

static __device__ __forceinline__ float fast_tanh(float x) {
    // tanh(x) = 1 - 2/(exp(2x)+1); exp(2x) = exp2(x * 2*log2(e))
    float e = __builtin_amdgcn_exp2f(x * 2.8853900817779268f);
    return 1.0f - 2.0f * __builtin_amdgcn_rcpf(e + 1.0f);
}
static __device__ __forceinline__ unsigned pkrtz(float a, float b) {
    f16x2 h = __builtin_amdgcn_cvt_pkrtz(a, b);     // v_cvt_pkrtz_f16_f32
    return __builtin_bit_cast(unsigned, h);
}
static __device__ __forceinline__ void pkfma(f32x2& a, float s, f32x2 k) {
    f32x2 sv = {s, s};
    a = __builtin_elementwise_fma(sv, k, a);        // v_pk_fma_f32
}

// LDS layout: fp16, transposed. Column c of wave w's 8 rows = one 16B slot:
//   slot(c,w) = (c<<2) ^ ((c>>2)&3) ^ w      (XOR bijective in w -> race-free,
//   no __syncthreads anywhere; c-derived bits spread gather bank-groups)
#define SOFF(c) ((((c) << 2) ^ (((c) >> 2) & 3)) ^ w)

#define UNPK(u, lo, hi) { f16x2 _h = __builtin_bit_cast(f16x2, (unsigned)(u)); \
                          lo = (float)_h[0]; hi = (float)_h[1]; }

#define DECL_ACC \
    f32x2 a0l={bv.x,bv.y}, a0h={bv.z,bv.w}, a1l=a0l, a1h=a0h, a2l=a0l, a2h=a0h, \
          a3l=a0l, a3h=a0h, a4l=a0l, a4h=a0h, a5l=a0l, a5h=a0h, a6l=a0l, a6h=a0h, \
          a7l=a0l, a7h=a0h;

#define FMAP(p, kv) do { \
    const f32x2 klo = {kv.x, kv.y}, khi = {kv.z, kv.w}; \
    float s0,s1,s2,s3,s4,s5,s6,s7; \
    UNPK(p.x, s0, s1) UNPK(p.y, s2, s3) UNPK(p.z, s4, s5) UNPK(p.w, s6, s7) \
    pkfma(a0l,s0,klo); pkfma(a0h,s0,khi); pkfma(a1l,s1,klo); pkfma(a1h,s1,khi); \
    pkfma(a2l,s2,klo); pkfma(a2h,s2,khi); pkfma(a3l,s3,klo); pkfma(a3h,s3,khi); \
    pkfma(a4l,s4,klo); pkfma(a4h,s4,khi); pkfma(a5l,s5,klo); pkfma(a5h,s5,khi); \
    pkfma(a6l,s6,klo); pkfma(a6h,s6,khi); pkfma(a7l,s7,klo); pkfma(a7h,s7,khi); \
} while (0)

#define APPLY_TANH \
    a0l.x=fast_tanh(a0l.x); a0l.y=fast_tanh(a0l.y); a0h.x=fast_tanh(a0h.x); a0h.y=fast_tanh(a0h.y); \
    a1l.x=fast_tanh(a1l.x); a1l.y=fast_tanh(a1l.y); a1h.x=fast_tanh(a1h.x); a1h.y=fast_tanh(a1h.y); \
    a2l.x=fast_tanh(a2l.x); a2l.y=fast_tanh(a2l.y); a2h.x=fast_tanh(a2h.x); a2h.y=fast_tanh(a2h.y); \
    a3l.x=fast_tanh(a3l.x); a3l.y=fast_tanh(a3l.y); a3h.x=fast_tanh(a3h.x); a3h.y=fast_tanh(a3h.y); \
    a4l.x=fast_tanh(a4l.x); a4l.y=fast_tanh(a4l.y); a4h.x=fast_tanh(a4h.x); a4h.y=fast_tanh(a4h.y); \
    a5l.x=fast_tanh(a5l.x); a5l.y=fast_tanh(a5l.y); a5h.x=fast_tanh(a5h.x); a5h.y=fast_tanh(a5h.y); \
    a6l.x=fast_tanh(a6l.x); a6l.y=fast_tanh(a6l.y); a6h.x=fast_tanh(a6h.x); a6h.y=fast_tanh(a6h.y); \
    a7l.x=fast_tanh(a7l.x); a7l.y=fast_tanh(a7l.y); a7h.x=fast_tanh(a7h.x); a7h.y=fast_tanh(a7h.y);

// One level: explicit pointers (no arrays, no l-loop -> nothing runtime-indexed)
#define LEVEL(Kp, Bp, Ip) \
    const float4* Kb = (const float4*)(Kp) + ((g * F) << 2) + qq;   /* f at Kb[f*4], 64B imm stride */ \
    const int4*   Ix = (const int4*)(Ip) + (g << 3); \
    const float4  bv = ((const float4*)(Bp))[(g << 2) + qq]; \
    DECL_ACC \
    _Pragma("unroll") \
    for (int j = 0; j < 8; ++j) { \
        const int4 ii = Ix[j]; \
        const int4 p0 = tile[SOFF(ii.x)];   /* ds_read_b128 = 8 rows */ \
        const int4 p1 = tile[SOFF(ii.y)]; \
        const int4 p2 = tile[SOFF(ii.z)]; \
        const int4 p3 = tile[SOFF(ii.w)]; \
        const float4 kA = Kb[(4*j+0) << 2]; \
        const float4 kB = Kb[(4*j+1) << 2]; \
        const float4 kC = Kb[(4*j+2) << 2]; \
        const float4 kD = Kb[(4*j+3) << 2]; \
        FMAP(p0, kA); FMAP(p1, kB); FMAP(p2, kC); FMAP(p3, kD); \
    } \
    APPLY_TANH

#define STORE_LDS(OB) do { \
    const int cb = (OB) + (g << 4) + (qq << 2); \
    tile[SOFF(cb+0)] = make_int4((int)pkrtz(a0l.x,a1l.x),(int)pkrtz(a2l.x,a3l.x),(int)pkrtz(a4l.x,a5l.x),(int)pkrtz(a6l.x,a7l.x)); \
    tile[SOFF(cb+1)] = make_int4((int)pkrtz(a0l.y,a1l.y),(int)pkrtz(a2l.y,a3l.y),(int)pkrtz(a4l.y,a5l.y),(int)pkrtz(a6l.y,a7l.y)); \
    tile[SOFF(cb+2)] = make_int4((int)pkrtz(a0h.x,a1h.x),(int)pkrtz(a2h.x,a3h.x),(int)pkrtz(a4h.x,a5h.x),(int)pkrtz(a6h.x,a7h.x)); \
    tile[SOFF(cb+3)] = make_int4((int)pkrtz(a0h.y,a1h.y),(int)pkrtz(a2h.y,a3h.y),(int)pkrtz(a4h.y,a5h.y),(int)pkrtz(a6h.y,a7h.y)); \
} while (0)

extern "C" __global__ __launch_bounds__(256, 3)
void denc_kernel(const float* __restrict__ x,
                 const float* __restrict__ k1, const float* __restrict__ b1, const int* __restrict__ i1,
                 const float* __restrict__ k2, const float* __restrict__ b2, const int* __restrict__ i2,
                 const float* __restrict__ k3, const float* __restrict__ b3, const int* __restrict__ i3,
                 const float* __restrict__ k4, const float* __restrict__ b4, const int* __restrict__ i4,
                 float* __restrict__ out)
{
    __shared__ int4 tile[TILE_I4];

    const int tid  = threadIdx.x;
    const int w    = tid >> 6;        // wave owns rows 8w..8w+7 of the block
    const int lane = tid & 63;
    const int g    = lane >> 2;       // group 0..15
    const int qq   = lane & 3;        // u-quad 0..3
    const int R0   = blockIdx.x * RPB;

    // ---- stage x: lane packs cols 4*lane..4*lane+3 of its wave's 8 rows ----
    {
        const float4* x4 = (const float4*)x + ((size_t)(R0 + 8 * w)) * 64 + lane;
        const float4 v0 = x4[0*64], v1 = x4[1*64], v2 = x4[2*64], v3 = x4[3*64];
        const float4 v4 = x4[4*64], v5 = x4[5*64], v6 = x4[6*64], v7 = x4[7*64];
        const int c0 = lane << 2;
#define PACKCOL(K_, CMP) tile[SOFF(c0 + K_)] = make_int4( \
            (int)pkrtz(v0.CMP, v1.CMP), (int)pkrtz(v2.CMP, v3.CMP), \
            (int)pkrtz(v4.CMP, v5.CMP), (int)pkrtz(v6.CMP, v7.CMP))
        PACKCOL(0, x); PACKCOL(1, y); PACKCOL(2, z); PACKCOL(3, w);
#undef PACKCOL
    }
    // No __syncthreads: every wave reads/writes only its own 16B slots (SOFF ^ w).

    { LEVEL(k1, b1, i1); STORE_LDS(NIN); }
    { LEVEL(k2, b2, i2); STORE_LDS(NIN + 256); }
    { LEVEL(k3, b3, i3); STORE_LDS(NIN + 512); }
    { LEVEL(k4, b4, i4);
      float4* o4 = (float4*)out + ((size_t)(R0 + 8 * w)) * 64 + (g << 2) + qq;
      o4[0*64] = make_float4(a0l.x, a0l.y, a0h.x, a0h.y);
      o4[1*64] = make_float4(a1l.x, a1l.y, a1h.x, a1h.y);
      o4[2*64] = make_float4(a2l.x, a2l.y, a2h.x, a2h.y);
      o4[3*64] = make_float4(a3l.x, a3l.y, a3h.x, a3h.y);
      o4[4*64] = make_float4(a4l.x, a4l.y, a4h.x, a4h.y);
      o4[5*64] = make_float4(a5l.x, a5l.y, a5h.x, a5h.y);
      o4[6*64] = make_float4(a6l.x, a6l.y, a6h.x, a6h.y);
      o4[7*64] = make_float4(a7l.x, a7l.y, a7h.x, a7h.y);
    }
}

extern "C" void kernel_launch(void* const* d_in, const int* in_sizes, int n_in,
                              void* d_out, int out_size, void* d_ws, size_t ws_size,
                              hipStream_t stream) {
    const float* x  = (const float*)d_in[0];
    const float* k1 = (const float*)d_in[1];
    const float* b1 = (const float*)d_in[2];
    const int*   i1 = (const int*)  d_in[3];
    const float* k2 = (const float*)d_in[4];
    const float* b2 = (const float*)d_in[5];
    const int*   i2 = (const int*)  d_in[6];
    const float* k3 = (const float*)d_in[7];
    const float* b3 = (const float*)d_in[8];
    const int*   i3 = (const int*)  d_in[9];
    const float* k4 = (const float*)d_in[10];
    const float* b4 = (const float*)d_in[11];
    const int*   i4 = (const int*)  d_in[12];
    float* out = (float*)d_out;

    const int batch = in_sizes[0] / NIN;      // 65536
    dim3 grid(batch / RPB);                   // 2048 blocks
    dim3 block(256);
    hipLaunchKernelGGL(denc_kernel, grid, block, 0, stream,
                       x, k1, b1, i1, k2, b2, i2, k3, b3, i3, k4, b4, i4, out);
}

// Round 7
// 64.801 us; speedup vs baseline: 2.2719x; 1.3139x over previous
//
#include <hip/hip_runtime.h>
#include <stdint.h>

#define NIN 256
#define RPB 32              // rows per block: 2 row-halves x 16

typedef float    f32x4 __attribute__((ext_vector_type(4)));
typedef _Float16 half8 __attribute__((ext_vector_type(8)));
typedef __fp16   h8    __attribute__((ext_vector_type(8)));
typedef __fp16   fp16x2 __attribute__((ext_vector_type(2)));
typedef uint32_t u32x4 __attribute__((ext_vector_type(4)));

static __device__ __forceinline__ float fast_tanh(float x) {
    // tanh(x) = 1 - 2/(exp(2x)+1)
    float e = __builtin_amdgcn_exp2f(x * 2.8853900817779268f);
    return 1.0f - 2.0f * __builtin_amdgcn_rcpf(e + 1.0f);
}
static __device__ __forceinline__ unsigned pkrtz(float a, float b) {
    fp16x2 h = __builtin_amdgcn_cvt_pkrtz(a, b);
    return __builtin_bit_cast(unsigned, h);
}

// ---- prep: kt[lvl][g][q][n][e] = (fp16) K_lvl[g][ q*8+e ][ n ]  (identity k-order)
// B-frag for mfma_f32_16x16x32_f16: lane (q,n) holds B[k=q*8+e][col=n], e ascending.
extern "C" __global__ void kprep_kernel(const float* __restrict__ k1, const float* __restrict__ k2,
                                        const float* __restrict__ k3, const float* __restrict__ k4,
                                        uint32_t* __restrict__ kt) {
    const int bx  = blockIdx.x;                       // 16 blocks x 256
    const int lvl = bx >> 2;
    const float* Kp = (lvl == 0) ? k1 : (lvl == 1) ? k2 : (lvl == 2) ? k3 : k4;
    const int sub = (bx & 3) * 256 + threadIdx.x;     // 0..1023 = g*64 + q*16 + n
    const int g = sub >> 6, q = (sub >> 4) & 3, n = sub & 15;
    const float* src = Kp + (size_t)(g * 32 + q * 8) * 16 + n;
    const float v0 = src[0],  v1 = src[16], v2 = src[32], v3 = src[48];
    const float v4 = src[64], v5 = src[80], v6 = src[96], v7 = src[112];
    u32x4 pk;
    pk.x = pkrtz(v0, v1); pk.y = pkrtz(v2, v3);
    pk.z = pkrtz(v4, v5); pk.w = pkrtz(v6, v7);
    *(u32x4*)(kt + (size_t)(lvl * 1024 + sub) * 4) = pk;
}

// ---- main ----
// ftile: col-major fp16, 32 rows/col = 4 int4 slots (8 rows each):
//   slot(col, rb) = col*4 + (rb ^ ((col>>1)&3))     rb = rowblock 0..3
// A-fragment gathered directly: lane (q,n) reads sel[row=n][k=q*8+e] via 8x ds_read_u16.

extern "C" __global__ __launch_bounds__(256, 2)
void denc_kernel(const float* __restrict__ x,
                 const int* __restrict__ i1, const float* __restrict__ b1,
                 const int* __restrict__ i2, const float* __restrict__ b2,
                 const int* __restrict__ i3, const float* __restrict__ b3,
                 const int* __restrict__ i4, const float* __restrict__ b4,
                 const uint32_t* __restrict__ kt,
                 float* __restrict__ out)
{
    __shared__ int4 ftile[4096];                     // 64 KB
    const __fp16* t16 = (const __fp16*)ftile;

    const int tid  = threadIdx.x;
    const int w    = tid >> 6;
    const int lane = tid & 63;
    const int q    = lane >> 4;                      // k-block 0..3
    const int n    = lane & 15;                      // A row / B,D col
    const int rows16 = (w >> 1) << 4;                // which 16-row half
    const int gbase  = (w & 1) << 3;                 // which 8 groups
    const int R0   = blockIdx.x * RPB;
    const int rbn  = ((w >> 1) << 1) + (n >> 3);     // rowblock of my MFMA row
    const int rlo  = n & 7;                          // fp16 elem within slot

    // ---- stage x: thread packs rowblock (tid>>6), cols 4*(tid&63).. ----
    {
        const int c  = tid & 63;
        const int sw = tid >> 6;
        const float4* x4 = (const float4*)x + (size_t)(R0 + sw * 8) * 64 + c;
        float4 v0 = x4[0*64], v1 = x4[1*64], v2 = x4[2*64], v3 = x4[3*64];
        float4 v4 = x4[4*64], v5 = x4[5*64], v6 = x4[6*64], v7 = x4[7*64];
        #pragma unroll
        for (int cc = 0; cc < 4; ++cc) {
            const int col = c * 4 + cc;
            int4 pk_;
            pk_.x = (int)pkrtz((&v0.x)[cc], (&v1.x)[cc]);
            pk_.y = (int)pkrtz((&v2.x)[cc], (&v3.x)[cc]);
            pk_.z = (int)pkrtz((&v4.x)[cc], (&v5.x)[cc]);
            pk_.w = (int)pkrtz((&v6.x)[cc], (&v7.x)[cc]);
            ftile[col * 4 + (sw ^ ((col >> 1) & 3))] = pk_;
        }
    }

    f32x4 acc[8];
    u32x4 bf[8];

#define EOFF(c) (((c) << 5) + ((rbn ^ (((c) >> 1) & 3)) << 3) + rlo)

#define GFRAG(gi, Ip) ({ \
    const int4 ia = *(const int4*)((Ip) + (gbase + (gi)) * 32 + q * 8); \
    const int4 ib = *(const int4*)((Ip) + (gbase + (gi)) * 32 + q * 8 + 4); \
    h8 av; \
    av[0] = t16[EOFF(ia.x)]; av[1] = t16[EOFF(ia.y)]; \
    av[2] = t16[EOFF(ia.z)]; av[3] = t16[EOFF(ia.w)]; \
    av[4] = t16[EOFF(ib.x)]; av[5] = t16[EOFF(ib.y)]; \
    av[6] = t16[EOFF(ib.z)]; av[7] = t16[EOFF(ib.w)]; \
    av; })

#define LEVEL(Ip, Bp, LVLBASE, OB, LAST) do { \
    __syncthreads(); \
    _Pragma("unroll") \
    for (int g = 0; g < 8; ++g) { \
        bf[g] = *(const u32x4*)(kt + (size_t)((LVLBASE) + (gbase + g) * 64 + q * 16 + n) * 4); \
        const float bvv = (Bp)[(gbase + g) * 16 + n]; \
        acc[g] = (f32x4){bvv, bvv, bvv, bvv}; \
    } \
    _Pragma("unroll") \
    for (int g = 0; g < 8; ++g) { \
        h8 av = GFRAG(g, Ip); \
        acc[g] = __builtin_amdgcn_mfma_f32_16x16x32_f16( \
            __builtin_bit_cast(half8, av), __builtin_bit_cast(half8, bf[g]), acc[g], 0, 0, 0); \
    } \
    _Pragma("unroll") \
    for (int g = 0; g < 8; ++g) { \
        const float u0 = fast_tanh(acc[g][0]), u1 = fast_tanh(acc[g][1]); \
        const float u2 = fast_tanh(acc[g][2]), u3 = fast_tanh(acc[g][3]); \
        if (LAST) { \
            float* ob = out + (size_t)(R0 + rows16 + q * 4) * 256 + (gbase + g) * 16 + n; \
            ob[0] = u0; ob[256] = u1; ob[512] = u2; ob[768] = u3; \
        } else { \
            const int col = (OB) + (gbase + g) * 16 + n; \
            const int rb  = ((w >> 1) << 1) + (q >> 1); \
            int2 pv; pv.x = (int)pkrtz(u0, u1); pv.y = (int)pkrtz(u2, u3); \
            *(int2*)((char*)ftile + col * 64 + ((rb ^ ((col >> 1) & 3)) << 4) + (q & 1) * 8) = pv; \
        } \
    } \
} while (0)

    LEVEL(i1, b1,    0, NIN,       0);
    LEVEL(i2, b2, 1024, NIN + 256, 0);
    LEVEL(i3, b3, 2048, NIN + 512, 0);
    LEVEL(i4, b4, 3072, 0,         1);

#undef LEVEL
#undef GFRAG
#undef EOFF
}

extern "C" void kernel_launch(void* const* d_in, const int* in_sizes, int n_in,
                              void* d_out, int out_size, void* d_ws, size_t ws_size,
                              hipStream_t stream) {
    const float* x  = (const float*)d_in[0];
    const float* k1 = (const float*)d_in[1];
    const float* b1 = (const float*)d_in[2];
    const int*   i1 = (const int*)  d_in[3];
    const float* k2 = (const float*)d_in[4];
    const float* b2 = (const float*)d_in[5];
    const int*   i2 = (const int*)  d_in[6];
    const float* k3 = (const float*)d_in[7];
    const float* b3 = (const float*)d_in[8];
    const int*   i3 = (const int*)  d_in[9];
    const float* k4 = (const float*)d_in[10];
    const float* b4 = (const float*)d_in[11];
    const int*   i4 = (const int*)  d_in[12];
    float* out = (float*)d_out;
    uint32_t* kt = (uint32_t*)d_ws;                  // 64 KB scratch

    hipLaunchKernelGGL(kprep_kernel, dim3(16), dim3(256), 0, stream,
                       k1, k2, k3, k4, kt);

    const int batch = in_sizes[0] / NIN;             // 65536
    hipLaunchKernelGGL(denc_kernel, dim3(batch / RPB), dim3(256), 0, stream,
                       x, i1, b1, i2, b2, i3, b3, i4, b4,
                       (const uint32_t*)kt, out);
}

// Round 8
// 56.397 us; speedup vs baseline: 2.6104x; 1.1490x over previous
//
#include <hip/hip_runtime.h>
#include <stdint.h>

#define NIN 256
#define RPB 32              // rows per block: 2 row-halves x 16

typedef float    f32x4 __attribute__((ext_vector_type(4)));
typedef _Float16 half8 __attribute__((ext_vector_type(8)));
typedef __fp16   h8    __attribute__((ext_vector_type(8)));
typedef __fp16   fp16x2 __attribute__((ext_vector_type(2)));
typedef uint32_t u32x4 __attribute__((ext_vector_type(4)));

static __device__ __forceinline__ float fast_tanh(float x) {
    // tanh(x) = 1 - 2/(exp(2x)+1)
    float e = __builtin_amdgcn_exp2f(x * 2.8853900817779268f);
    return 1.0f - 2.0f * __builtin_amdgcn_rcpf(e + 1.0f);
}
static __device__ __forceinline__ unsigned pkrtz(float a, float b) {
    fp16x2 h = __builtin_amdgcn_cvt_pkrtz(a, b);
    return __builtin_bit_cast(unsigned, h);
}

// ---- prep: kt[lvl][g][q][n][e] = (fp16) K_lvl[g][ q*8+e ][ n ]  (identity k-order)
//      apre[lvl][g][f] = (col<<6) | (((col>>1)&3)<<4)   (swizzled gather byte-base)
extern "C" __global__ void kprep_kernel(const float* __restrict__ k1, const float* __restrict__ k2,
                                        const float* __restrict__ k3, const float* __restrict__ k4,
                                        const int* __restrict__ i1, const int* __restrict__ i2,
                                        const int* __restrict__ i3, const int* __restrict__ i4,
                                        uint32_t* __restrict__ kt, int* __restrict__ apre) {
    const int bx  = blockIdx.x;                       // 16 blocks x 256
    const int lvl = bx >> 2;
    const float* Kp = (lvl == 0) ? k1 : (lvl == 1) ? k2 : (lvl == 2) ? k3 : k4;
    const int*   Ip = (lvl == 0) ? i1 : (lvl == 1) ? i2 : (lvl == 2) ? i3 : i4;
    const int sub = (bx & 3) * 256 + threadIdx.x;     // 0..1023 = g*64 + q*16 + n
    const int g = sub >> 6, q = (sub >> 4) & 3, n = sub & 15;
    const float* src = Kp + (size_t)(g * 32 + q * 8) * 16 + n;
    const float v0 = src[0],  v1 = src[16], v2 = src[32], v3 = src[48];
    const float v4 = src[64], v5 = src[80], v6 = src[96], v7 = src[112];
    u32x4 pk;
    pk.x = pkrtz(v0, v1); pk.y = pkrtz(v2, v3);
    pk.z = pkrtz(v4, v5); pk.w = pkrtz(v6, v7);
    *(u32x4*)(kt + (size_t)(lvl * 1024 + sub) * 4) = pk;

    if ((bx & 3) < 2) {                               // 512 idx entries per level
        const int f = (bx & 3) * 256 + threadIdx.x;
        const int col = Ip[f];
        apre[lvl * 512 + f] = (col << 6) | (((col >> 1) & 3) << 4);
    }
}

// ---- main ----
// ftile: col-major fp16, 32 rows/col = 4 int4 slots (8 rows each):
//   slot(col, rb) = col*4 + (rb ^ ((col>>1)&3))     rb = rowblock 0..3
// Gather byte addr = apre[col] ^ Lf,  Lf = (rbn<<4)|(rlo<<1)  (bits disjoint/XOR-aligned).

extern "C" __global__ __launch_bounds__(256, 2)
void denc_kernel(const float* __restrict__ x,
                 const int* __restrict__ a1, const float* __restrict__ b1,
                 const int* __restrict__ a2, const float* __restrict__ b2,
                 const int* __restrict__ a3, const float* __restrict__ b3,
                 const int* __restrict__ a4, const float* __restrict__ b4,
                 const uint32_t* __restrict__ kt,
                 float* __restrict__ out)
{
    __shared__ int4 ftile[4096];                     // 64 KB
    const char* tfc = (const char*)ftile;

    const int tid  = threadIdx.x;
    const int w    = tid >> 6;
    const int lane = tid & 63;
    const int q    = lane >> 4;                      // k-block 0..3
    const int n    = lane & 15;                      // A row / B,D col
    const int rows16 = (w >> 1) << 4;                // which 16-row half
    const int gbase  = (w & 1) << 3;                 // which 8 groups
    const int R0   = blockIdx.x * RPB;
    const int rbn  = ((w >> 1) << 1) + (n >> 3);     // rowblock of my MFMA row
    const int Lf   = (rbn << 4) | ((n & 7) << 1);    // lane part of gather addr

    // ---- stage x: thread packs rowblock (tid>>6), cols 4*(tid&63).. ----
    {
        const int c  = tid & 63;
        const int sw = tid >> 6;
        const float4* x4 = (const float4*)x + (size_t)(R0 + sw * 8) * 64 + c;
        float4 v0 = x4[0*64], v1 = x4[1*64], v2 = x4[2*64], v3 = x4[3*64];
        float4 v4 = x4[4*64], v5 = x4[5*64], v6 = x4[6*64], v7 = x4[7*64];
        #pragma unroll
        for (int cc = 0; cc < 4; ++cc) {
            const int col = c * 4 + cc;
            int4 pk_;
            pk_.x = (int)pkrtz((&v0.x)[cc], (&v1.x)[cc]);
            pk_.y = (int)pkrtz((&v2.x)[cc], (&v3.x)[cc]);
            pk_.z = (int)pkrtz((&v4.x)[cc], (&v5.x)[cc]);
            pk_.w = (int)pkrtz((&v6.x)[cc], (&v7.x)[cc]);
            ftile[col * 4 + (sw ^ ((col >> 1) & 3))] = pk_;
        }
    }

    f32x4 acc[8];
    u32x4 bf[8];

#define GFRAG(gi, Ap) ({ \
    const int4 pa = *(const int4*)((Ap) + (gbase + (gi)) * 32 + q * 8); \
    const int4 pb = *(const int4*)((Ap) + (gbase + (gi)) * 32 + q * 8 + 4); \
    h8 av; \
    av[0] = *(const __fp16*)(tfc + (pa.x ^ Lf)); \
    av[1] = *(const __fp16*)(tfc + (pa.y ^ Lf)); \
    av[2] = *(const __fp16*)(tfc + (pa.z ^ Lf)); \
    av[3] = *(const __fp16*)(tfc + (pa.w ^ Lf)); \
    av[4] = *(const __fp16*)(tfc + (pb.x ^ Lf)); \
    av[5] = *(const __fp16*)(tfc + (pb.y ^ Lf)); \
    av[6] = *(const __fp16*)(tfc + (pb.z ^ Lf)); \
    av[7] = *(const __fp16*)(tfc + (pb.w ^ Lf)); \
    av; })

#define LEVEL(Ap, Bp, LVLBASE, OB, LAST) do { \
    __syncthreads(); \
    _Pragma("unroll") \
    for (int g = 0; g < 8; ++g) { \
        bf[g] = *(const u32x4*)(kt + (size_t)((LVLBASE) + (gbase + g) * 64 + q * 16 + n) * 4); \
        const float bvv = (Bp)[(gbase + g) * 16 + n]; \
        acc[g] = (f32x4){bvv, bvv, bvv, bvv}; \
    } \
    _Pragma("unroll") \
    for (int g = 0; g < 8; ++g) { \
        h8 av = GFRAG(g, Ap); \
        acc[g] = __builtin_amdgcn_mfma_f32_16x16x32_f16( \
            __builtin_bit_cast(half8, av), __builtin_bit_cast(half8, bf[g]), acc[g], 0, 0, 0); \
    } \
    _Pragma("unroll") \
    for (int g = 0; g < 8; ++g) { \
        const float u0 = fast_tanh(acc[g][0]), u1 = fast_tanh(acc[g][1]); \
        const float u2 = fast_tanh(acc[g][2]), u3 = fast_tanh(acc[g][3]); \
        if (LAST) { \
            float* ob = out + (size_t)(R0 + rows16 + q * 4) * 256 + (gbase + g) * 16 + n; \
            ob[0] = u0; ob[256] = u1; ob[512] = u2; ob[768] = u3; \
        } else { \
            const int col = (OB) + (gbase + g) * 16 + n; \
            const int rb  = ((w >> 1) << 1) + (q >> 1); \
            int2 pv; pv.x = (int)pkrtz(u0, u1); pv.y = (int)pkrtz(u2, u3); \
            *(int2*)((char*)ftile + col * 64 + ((rb ^ ((col >> 1) & 3)) << 4) + (q & 1) * 8) = pv; \
        } \
    } \
} while (0)

    LEVEL(a1, b1,    0, NIN,       0);
    LEVEL(a2, b2, 1024, NIN + 256, 0);
    LEVEL(a3, b3, 2048, NIN + 512, 0);
    LEVEL(a4, b4, 3072, 0,         1);

#undef LEVEL
#undef GFRAG
}

extern "C" void kernel_launch(void* const* d_in, const int* in_sizes, int n_in,
                              void* d_out, int out_size, void* d_ws, size_t ws_size,
                              hipStream_t stream) {
    const float* x  = (const float*)d_in[0];
    const float* k1 = (const float*)d_in[1];
    const float* b1 = (const float*)d_in[2];
    const int*   i1 = (const int*)  d_in[3];
    const float* k2 = (const float*)d_in[4];
    const float* b2 = (const float*)d_in[5];
    const int*   i2 = (const int*)  d_in[6];
    const float* k3 = (const float*)d_in[7];
    const float* b3 = (const float*)d_in[8];
    const int*   i3 = (const int*)  d_in[9];
    const float* k4 = (const float*)d_in[10];
    const float* b4 = (const float*)d_in[11];
    const int*   i4 = (const int*)  d_in[12];
    float* out = (float*)d_out;
    uint32_t* kt = (uint32_t*)d_ws;                  // 64 KB
    int* apre = (int*)((char*)d_ws + 65536);         // 8 KB

    hipLaunchKernelGGL(kprep_kernel, dim3(16), dim3(256), 0, stream,
                       k1, k2, k3, k4, i1, i2, i3, i4, kt, apre);

    const int batch = in_sizes[0] / NIN;             // 65536
    hipLaunchKernelGGL(denc_kernel, dim3(batch / RPB), dim3(256), 0, stream,
                       x, apre, b1, apre + 512, b2, apre + 1024, b3, apre + 1536, b4,
                       (const uint32_t*)kt, out);
}

// Round 9
// 49.140 us; speedup vs baseline: 2.9959x; 1.1477x over previous
//
#include <hip/hip_runtime.h>
#include <stdint.h>

#define NIN 256
#define RPB 16              // rows per block: one 16-row MFMA tile

typedef float    f32x4 __attribute__((ext_vector_type(4)));
typedef _Float16 half8 __attribute__((ext_vector_type(8)));
typedef __fp16   h8    __attribute__((ext_vector_type(8)));
typedef __fp16   fp16x2 __attribute__((ext_vector_type(2)));
typedef uint32_t u32x4 __attribute__((ext_vector_type(4)));

static __device__ __forceinline__ float fast_tanh(float x) {
    // tanh(x) = 1 - 2/(exp(2x)+1)
    float e = __builtin_amdgcn_exp2f(x * 2.8853900817779268f);
    return 1.0f - 2.0f * __builtin_amdgcn_rcpf(e + 1.0f);
}
static __device__ __forceinline__ unsigned pkrtz(float a, float b) {
    fp16x2 h = __builtin_amdgcn_cvt_pkrtz(a, b);
    return __builtin_bit_cast(unsigned, h);
}

// ---- prep: kt[lvl][g][q][n][e] = (fp16) K_lvl[g][ q*8+e ][ n ]  (identity k-order)
//      apre[lvl][g][f] = (col<<5) | ((col&1)<<4)   (swizzled gather byte-base, 2-slot layout)
extern "C" __global__ void kprep_kernel(const float* __restrict__ k1, const float* __restrict__ k2,
                                        const float* __restrict__ k3, const float* __restrict__ k4,
                                        const int* __restrict__ i1, const int* __restrict__ i2,
                                        const int* __restrict__ i3, const int* __restrict__ i4,
                                        uint32_t* __restrict__ kt, int* __restrict__ apre) {
    const int bx  = blockIdx.x;                       // 16 blocks x 256
    const int lvl = bx >> 2;
    const float* Kp = (lvl == 0) ? k1 : (lvl == 1) ? k2 : (lvl == 2) ? k3 : k4;
    const int*   Ip = (lvl == 0) ? i1 : (lvl == 1) ? i2 : (lvl == 2) ? i3 : i4;
    const int sub = (bx & 3) * 256 + threadIdx.x;     // 0..1023 = g*64 + q*16 + n
    const int g = sub >> 6, q = (sub >> 4) & 3, n = sub & 15;
    const float* src = Kp + (size_t)(g * 32 + q * 8) * 16 + n;
    const float v0 = src[0],  v1 = src[16], v2 = src[32], v3 = src[48];
    const float v4 = src[64], v5 = src[80], v6 = src[96], v7 = src[112];
    u32x4 pk;
    pk.x = pkrtz(v0, v1); pk.y = pkrtz(v2, v3);
    pk.z = pkrtz(v4, v5); pk.w = pkrtz(v6, v7);
    *(u32x4*)(kt + (size_t)(lvl * 1024 + sub) * 4) = pk;

    if ((bx & 3) < 2) {                               // 512 idx entries per level
        const int f = (bx & 3) * 256 + threadIdx.x;
        const int col = Ip[f];
        apre[lvl * 512 + f] = (col << 5) | ((col & 1) << 4);
    }
}

// ---- main ----
// ftile: col-major fp16, 16 rows/col = 2 int4 slots (8 rows each):
//   byte(row, col) = col*32 + (((row>>3) ^ (col&1))<<4) + (row&7)*2
// Gather byte addr = apre[col] ^ Lf,  Lf = ((n>>3)<<4)|((n&7)<<1).

extern "C" __global__ __launch_bounds__(256, 4)
void denc_kernel(const float* __restrict__ x,
                 const int* __restrict__ a1, const float* __restrict__ b1,
                 const int* __restrict__ a2, const float* __restrict__ b2,
                 const int* __restrict__ a3, const float* __restrict__ b3,
                 const int* __restrict__ a4, const float* __restrict__ b4,
                 const uint32_t* __restrict__ kt,
                 float* __restrict__ out)
{
    __shared__ int4 ftile[2048];                     // 32 KB -> 5 blocks/CU
    const char* tfc = (const char*)ftile;

    const int tid  = threadIdx.x;
    const int w    = tid >> 6;
    const int lane = tid & 63;
    const int q    = lane >> 4;                      // k-block 0..3 / D row-quad
    const int n    = lane & 15;                      // A row / B,D col
    const int gbase = w * 4;                         // wave owns 4 groups
    const int R0   = blockIdx.x * RPB;
    const int Lf   = ((n >> 3) << 4) | ((n & 7) << 1);   // lane part of gather addr

    // ---- stage x: thread packs rowblock (tid>>7), float2-cols (tid&127) ----
    {
        const int rb = tid >> 7;                     // 8-row block 0/1
        const int c2 = tid & 127;                    // float2 col 0..127
        const float2* x2 = (const float2*)x + (size_t)(R0 + rb * 8) * 128 + c2;
        float2 v0 = x2[0*128], v1 = x2[1*128], v2 = x2[2*128], v3 = x2[3*128];
        float2 v4 = x2[4*128], v5 = x2[5*128], v6 = x2[6*128], v7 = x2[7*128];
        #pragma unroll
        for (int cc = 0; cc < 2; ++cc) {
            const int col = c2 * 2 + cc;
            int4 pk_;
            pk_.x = (int)pkrtz((&v0.x)[cc], (&v1.x)[cc]);
            pk_.y = (int)pkrtz((&v2.x)[cc], (&v3.x)[cc]);
            pk_.z = (int)pkrtz((&v4.x)[cc], (&v5.x)[cc]);
            pk_.w = (int)pkrtz((&v6.x)[cc], (&v7.x)[cc]);
            ftile[col * 2 + (rb ^ (col & 1))] = pk_;
        }
    }

    f32x4 acc[4];
    u32x4 bf[4];

#define GFRAG(gi, Ap) ({ \
    const int4 pa = *(const int4*)((Ap) + (gbase + (gi)) * 32 + q * 8); \
    const int4 pb = *(const int4*)((Ap) + (gbase + (gi)) * 32 + q * 8 + 4); \
    h8 av; \
    av[0] = *(const __fp16*)(tfc + (pa.x ^ Lf)); \
    av[1] = *(const __fp16*)(tfc + (pa.y ^ Lf)); \
    av[2] = *(const __fp16*)(tfc + (pa.z ^ Lf)); \
    av[3] = *(const __fp16*)(tfc + (pa.w ^ Lf)); \
    av[4] = *(const __fp16*)(tfc + (pb.x ^ Lf)); \
    av[5] = *(const __fp16*)(tfc + (pb.y ^ Lf)); \
    av[6] = *(const __fp16*)(tfc + (pb.z ^ Lf)); \
    av[7] = *(const __fp16*)(tfc + (pb.w ^ Lf)); \
    av; })

#define LEVEL(Ap, Bp, LVLBASE, OB, LAST) do { \
    __syncthreads(); \
    _Pragma("unroll") \
    for (int g = 0; g < 4; ++g) { \
        bf[g] = *(const u32x4*)(kt + (size_t)((LVLBASE) + (gbase + g) * 64 + q * 16 + n) * 4); \
        const float bvv = (Bp)[(gbase + g) * 16 + n]; \
        acc[g] = (f32x4){bvv, bvv, bvv, bvv}; \
    } \
    _Pragma("unroll") \
    for (int g = 0; g < 4; ++g) { \
        h8 av = GFRAG(g, Ap); \
        acc[g] = __builtin_amdgcn_mfma_f32_16x16x32_f16( \
            __builtin_bit_cast(half8, av), __builtin_bit_cast(half8, bf[g]), acc[g], 0, 0, 0); \
    } \
    _Pragma("unroll") \
    for (int g = 0; g < 4; ++g) { \
        const float u0 = fast_tanh(acc[g][0]), u1 = fast_tanh(acc[g][1]); \
        const float u2 = fast_tanh(acc[g][2]), u3 = fast_tanh(acc[g][3]); \
        if (LAST) { \
            float* ob = out + (size_t)(R0 + q * 4) * 256 + (gbase + g) * 16 + n; \
            ob[0] = u0; ob[256] = u1; ob[512] = u2; ob[768] = u3; \
        } else { \
            const int col = (OB) + (gbase + g) * 16 + n; \
            int2 pv; pv.x = (int)pkrtz(u0, u1); pv.y = (int)pkrtz(u2, u3); \
            *(int2*)((char*)ftile + col * 32 + (((q >> 1) ^ (col & 1)) << 4) + (q & 1) * 8) = pv; \
        } \
    } \
} while (0)

    LEVEL(a1, b1,    0, NIN,       0);
    LEVEL(a2, b2, 1024, NIN + 256, 0);
    LEVEL(a3, b3, 2048, NIN + 512, 0);
    LEVEL(a4, b4, 3072, 0,         1);

#undef LEVEL
#undef GFRAG
}

extern "C" void kernel_launch(void* const* d_in, const int* in_sizes, int n_in,
                              void* d_out, int out_size, void* d_ws, size_t ws_size,
                              hipStream_t stream) {
    const float* x  = (const float*)d_in[0];
    const float* k1 = (const float*)d_in[1];
    const float* b1 = (const float*)d_in[2];
    const int*   i1 = (const int*)  d_in[3];
    const float* k2 = (const float*)d_in[4];
    const float* b2 = (const float*)d_in[5];
    const int*   i2 = (const int*)  d_in[6];
    const float* k3 = (const float*)d_in[7];
    const float* b3 = (const float*)d_in[8];
    const int*   i3 = (const int*)  d_in[9];
    const float* k4 = (const float*)d_in[10];
    const float* b4 = (const float*)d_in[11];
    const int*   i4 = (const int*)  d_in[12];
    float* out = (float*)d_out;
    uint32_t* kt = (uint32_t*)d_ws;                  // 64 KB
    int* apre = (int*)((char*)d_ws + 65536);         // 8 KB

    hipLaunchKernelGGL(kprep_kernel, dim3(16), dim3(256), 0, stream,
                       k1, k2, k3, k4, i1, i2, i3, i4, kt, apre);

    const int batch = in_sizes[0] / NIN;             // 65536
    hipLaunchKernelGGL(denc_kernel, dim3(batch / RPB), dim3(256), 0, stream,
                       x, apre, b1, apre + 512, b2, apre + 1024, b3, apre + 1536, b4,
                       (const uint32_t*)kt, out);
}

// Round 10
// 44.294 us; speedup vs baseline: 3.3237x; 1.1094x over previous
//
#include <hip/hip_runtime.h>
#include <stdint.h>

#define NIN 256
#define RPB 32              // rows per block: two 16-row MFMA tiles, row-paired

typedef float    f32x4 __attribute__((ext_vector_type(4)));
typedef _Float16 half8 __attribute__((ext_vector_type(8)));
typedef __fp16   fp16x2 __attribute__((ext_vector_type(2)));
typedef uint32_t u32x4 __attribute__((ext_vector_type(4)));

#define SEL_LO 0x05040100u   // v_perm: [b0.lo16, b1... -> lo halves of (g0,g1)
#define SEL_HI 0x07060302u   // hi halves

static __device__ __forceinline__ float fast_tanh(float x) {
    // tanh(x) = 1 - 2/(exp(2x)+1)
    float e = __builtin_amdgcn_exp2f(x * 2.8853900817779268f);
    return 1.0f - 2.0f * __builtin_amdgcn_rcpf(e + 1.0f);
}
static __device__ __forceinline__ unsigned pkrtz(float a, float b) {
    fp16x2 h = __builtin_amdgcn_cvt_pkrtz(a, b);    // lo=a (T0), hi=b (T1)
    return __builtin_bit_cast(unsigned, h);
}

// ---- prep: kt[lvl][g][q][n][e] = (fp16) K_lvl[g][ q*8+e ][ n ]  (identity k-order)
//      apre[lvl][g][f] = (col<<6) ^ (((col>>1)&3)<<4)   (row-pair layout byte base)
extern "C" __global__ void kprep_kernel(const float* __restrict__ k1, const float* __restrict__ k2,
                                        const float* __restrict__ k3, const float* __restrict__ k4,
                                        const int* __restrict__ i1, const int* __restrict__ i2,
                                        const int* __restrict__ i3, const int* __restrict__ i4,
                                        uint32_t* __restrict__ kt, int* __restrict__ apre) {
    const int bx  = blockIdx.x;                       // 16 blocks x 256
    const int lvl = bx >> 2;
    const float* Kp = (lvl == 0) ? k1 : (lvl == 1) ? k2 : (lvl == 2) ? k3 : k4;
    const int*   Ip = (lvl == 0) ? i1 : (lvl == 1) ? i2 : (lvl == 2) ? i3 : i4;
    const int sub = (bx & 3) * 256 + threadIdx.x;     // 0..1023 = g*64 + q*16 + n
    const int g = sub >> 6, q = (sub >> 4) & 3, n = sub & 15;
    const float* src = Kp + (size_t)(g * 32 + q * 8) * 16 + n;
    const float v0 = src[0],  v1 = src[16], v2 = src[32], v3 = src[48];
    const float v4 = src[64], v5 = src[80], v6 = src[96], v7 = src[112];
    u32x4 pk;
    pk.x = pkrtz(v0, v1); pk.y = pkrtz(v2, v3);
    pk.z = pkrtz(v4, v5); pk.w = pkrtz(v6, v7);
    *(u32x4*)(kt + (size_t)(lvl * 1024 + sub) * 4) = pk;

    if ((bx & 3) < 2) {                               // 512 idx entries per level
        const int f = (bx & 3) * 256 + threadIdx.x;
        const int col = Ip[f];
        apre[lvl * 512 + f] = (col << 6) ^ (((col >> 1) & 3) << 4);
    }
}

// ---- main ----
// ftile: col-major, 16 row-PAIRS per col (pair p = fp16 rows (p, p+16) in one u32):
//   byte(pair p, col) = (col<<6) ^ (((col>>1)&3)<<4) ^ (p<<2)
// One ds_read_b32 = A-frag element (row n) for BOTH 16-row tiles.

extern "C" __global__ __launch_bounds__(512, 4)
void denc_kernel(const float* __restrict__ x,
                 const int* __restrict__ a1, const float* __restrict__ b1,
                 const int* __restrict__ a2, const float* __restrict__ b2,
                 const int* __restrict__ a3, const float* __restrict__ b3,
                 const int* __restrict__ a4, const float* __restrict__ b4,
                 const uint32_t* __restrict__ kt,
                 float* __restrict__ out)
{
    __shared__ int4 ftile[4096];                     // 64 KB
    const char* tfc = (const char*)ftile;

    const int tid  = threadIdx.x;
    const int w    = tid >> 6;                       // 8 waves
    const int lane = tid & 63;
    const int q    = lane >> 4;                      // k-block / D row-quad
    const int n    = lane & 15;                      // A row-pair / B,D col
    const int gbase = w * 2;                         // wave owns 2 groups
    const int R0   = blockIdx.x * RPB;
    const int Ln   = n << 2;                         // lane part of gather addr

    // ---- stage x: thread t covers col c=t&255, pair-half ph=(t>>8)*8 ----
    {
        const int c  = tid & 255;
        const int ph = (tid >> 8) * 8;
        const float* xb = x + (size_t)R0 * 256 + c;
        uint32_t qp[8];
        #pragma unroll
        for (int j = 0; j < 8; ++j) {
            const float t0 = xb[(size_t)(ph + j) * 256];
            const float t1 = xb[(size_t)(ph + j + 16) * 256];
            qp[j] = pkrtz(t0, t1);
        }
        const int s = (c >> 1) & 3;
        ftile[c * 4 + ((ph >> 2) ^ s)]     = make_int4(qp[0], qp[1], qp[2], qp[3]);
        ftile[c * 4 + (((ph >> 2) + 1) ^ s)] = make_int4(qp[4], qp[5], qp[6], qp[7]);
    }

#define LEVEL(Ap, Bp, LVLBASE, OB, LAST) do { \
    __syncthreads(); \
    _Pragma("unroll") \
    for (int gi = 0; gi < 2; ++gi) { \
        const int gg = gbase + gi; \
        const u32x4 bf = *(const u32x4*)(kt + (size_t)((LVLBASE) + gg * 64 + q * 16 + n) * 4); \
        const float bvv = (Bp)[gg * 16 + n]; \
        f32x4 accA = {bvv, bvv, bvv, bvv}, accB = accA; \
        const int4 pa = *(const int4*)((Ap) + gg * 32 + q * 8); \
        const int4 pb = *(const int4*)((Ap) + gg * 32 + q * 8 + 4); \
        const uint32_t r0 = *(const uint32_t*)(tfc + (pa.x ^ Ln)); \
        const uint32_t r1 = *(const uint32_t*)(tfc + (pa.y ^ Ln)); \
        const uint32_t r2 = *(const uint32_t*)(tfc + (pa.z ^ Ln)); \
        const uint32_t r3 = *(const uint32_t*)(tfc + (pa.w ^ Ln)); \
        const uint32_t r4 = *(const uint32_t*)(tfc + (pb.x ^ Ln)); \
        const uint32_t r5 = *(const uint32_t*)(tfc + (pb.y ^ Ln)); \
        const uint32_t r6 = *(const uint32_t*)(tfc + (pb.z ^ Ln)); \
        const uint32_t r7 = *(const uint32_t*)(tfc + (pb.w ^ Ln)); \
        u32x4 fA, fB; \
        fA.x = __builtin_amdgcn_perm(r1, r0, SEL_LO); fB.x = __builtin_amdgcn_perm(r1, r0, SEL_HI); \
        fA.y = __builtin_amdgcn_perm(r3, r2, SEL_LO); fB.y = __builtin_amdgcn_perm(r3, r2, SEL_HI); \
        fA.z = __builtin_amdgcn_perm(r5, r4, SEL_LO); fB.z = __builtin_amdgcn_perm(r5, r4, SEL_HI); \
        fA.w = __builtin_amdgcn_perm(r7, r6, SEL_LO); fB.w = __builtin_amdgcn_perm(r7, r6, SEL_HI); \
        accA = __builtin_amdgcn_mfma_f32_16x16x32_f16( \
            __builtin_bit_cast(half8, fA), __builtin_bit_cast(half8, bf), accA, 0, 0, 0); \
        accB = __builtin_amdgcn_mfma_f32_16x16x32_f16( \
            __builtin_bit_cast(half8, fB), __builtin_bit_cast(half8, bf), accB, 0, 0, 0); \
        const float tA0 = fast_tanh(accA[0]), tA1 = fast_tanh(accA[1]); \
        const float tA2 = fast_tanh(accA[2]), tA3 = fast_tanh(accA[3]); \
        const float tB0 = fast_tanh(accB[0]), tB1 = fast_tanh(accB[1]); \
        const float tB2 = fast_tanh(accB[2]), tB3 = fast_tanh(accB[3]); \
        if (LAST) { \
            float* ob = out + (size_t)(R0 + q * 4) * 256 + gg * 16 + n; \
            ob[0]    = tA0; ob[256]  = tA1; ob[512]  = tA2; ob[768]  = tA3; \
            ob[4096] = tB0; ob[4352] = tB1; ob[4608] = tB2; ob[4864] = tB3; \
        } else { \
            const int col = (OB) + gg * 16 + n; \
            const int s = (col >> 1) & 3; \
            ftile[col * 4 + (q ^ s)] = make_int4( \
                pkrtz(tA0, tB0), pkrtz(tA1, tB1), pkrtz(tA2, tB2), pkrtz(tA3, tB3)); \
        } \
    } \
} while (0)

    LEVEL(a1, b1,    0, NIN,       0);
    LEVEL(a2, b2, 1024, NIN + 256, 0);
    LEVEL(a3, b3, 2048, NIN + 512, 0);
    LEVEL(a4, b4, 3072, 0,         1);

#undef LEVEL
}

extern "C" void kernel_launch(void* const* d_in, const int* in_sizes, int n_in,
                              void* d_out, int out_size, void* d_ws, size_t ws_size,
                              hipStream_t stream) {
    const float* x  = (const float*)d_in[0];
    const float* k1 = (const float*)d_in[1];
    const float* b1 = (const float*)d_in[2];
    const int*   i1 = (const int*)  d_in[3];
    const float* k2 = (const float*)d_in[4];
    const float* b2 = (const float*)d_in[5];
    const int*   i2 = (const int*)  d_in[6];
    const float* k3 = (const float*)d_in[7];
    const float* b3 = (const float*)d_in[8];
    const int*   i3 = (const int*)  d_in[9];
    const float* k4 = (const float*)d_in[10];
    const float* b4 = (const float*)d_in[11];
    const int*   i4 = (const int*)  d_in[12];
    float* out = (float*)d_out;
    uint32_t* kt = (uint32_t*)d_ws;                  // 64 KB
    int* apre = (int*)((char*)d_ws + 65536);         // 8 KB

    hipLaunchKernelGGL(kprep_kernel, dim3(16), dim3(256), 0, stream,
                       k1, k2, k3, k4, i1, i2, i3, i4, kt, apre);

    const int batch = in_sizes[0] / NIN;             // 65536
    hipLaunchKernelGGL(denc_kernel, dim3(batch / RPB), dim3(512), 0, stream,
                       x, apre, b1, apre + 512, b2, apre + 1024, b3, apre + 1536, b4,
                       (const uint32_t*)kt, out);
}

// Round 11
// 40.835 us; speedup vs baseline: 3.6053x; 1.0847x over previous
//
#include <hip/hip_runtime.h>
#include <stdint.h>

#define NIN 256
#define RPB 32              // rows per block: two 16-row MFMA tiles, row-paired

typedef float    f32x4 __attribute__((ext_vector_type(4)));
typedef _Float16 half8 __attribute__((ext_vector_type(8)));
typedef __fp16   fp16x2 __attribute__((ext_vector_type(2)));
typedef uint32_t u32x4 __attribute__((ext_vector_type(4)));

#define SEL_LO 0x05040100u   // v_perm: lo fp16 halves (tile A rows 0..15)
#define SEL_HI 0x07060302u   // hi fp16 halves (tile B rows 16..31)

static __device__ __forceinline__ float fast_tanh(float x) {
    // tanh(x) = 1 - 2/(exp(2x)+1)
    float e = __builtin_amdgcn_exp2f(x * 2.8853900817779268f);
    return 1.0f - 2.0f * __builtin_amdgcn_rcpf(e + 1.0f);
}
static __device__ __forceinline__ unsigned pkrtz(float a, float b) {
    fp16x2 h = __builtin_amdgcn_cvt_pkrtz(a, b);    // lo=a (tile A), hi=b (tile B)
    return __builtin_bit_cast(unsigned, h);
}

// ---- prep: kt[lvl][g][q][n][e] = (fp16) K_lvl[g][ q*8+e ][ n ]  (identity k-order)
//      apre[lvl][g][f] = (col<<6) ^ (((col>>1)&3)<<4)   (row-pair layout byte base)
extern "C" __global__ void kprep_kernel(const float* __restrict__ k1, const float* __restrict__ k2,
                                        const float* __restrict__ k3, const float* __restrict__ k4,
                                        const int* __restrict__ i1, const int* __restrict__ i2,
                                        const int* __restrict__ i3, const int* __restrict__ i4,
                                        uint32_t* __restrict__ kt, int* __restrict__ apre) {
    const int bx  = blockIdx.x;                       // 16 blocks x 256
    const int lvl = bx >> 2;
    const float* Kp = (lvl == 0) ? k1 : (lvl == 1) ? k2 : (lvl == 2) ? k3 : k4;
    const int*   Ip = (lvl == 0) ? i1 : (lvl == 1) ? i2 : (lvl == 2) ? i3 : i4;
    const int sub = (bx & 3) * 256 + threadIdx.x;     // 0..1023 = g*64 + q*16 + n
    const int g = sub >> 6, q = (sub >> 4) & 3, n = sub & 15;
    const float* src = Kp + (size_t)(g * 32 + q * 8) * 16 + n;
    const float v0 = src[0],  v1 = src[16], v2 = src[32], v3 = src[48];
    const float v4 = src[64], v5 = src[80], v6 = src[96], v7 = src[112];
    u32x4 pk;
    pk.x = pkrtz(v0, v1); pk.y = pkrtz(v2, v3);
    pk.z = pkrtz(v4, v5); pk.w = pkrtz(v6, v7);
    *(u32x4*)(kt + (size_t)(lvl * 1024 + sub) * 4) = pk;

    if ((bx & 3) < 2) {                               // 512 idx entries per level
        const int f = (bx & 3) * 256 + threadIdx.x;
        const int col = Ip[f];
        apre[lvl * 512 + f] = (col << 6) ^ (((col >> 1) & 3) << 4);
    }
}

// ---- main ----
// ftile: col-major, 16 row-PAIRS per col (pair p = fp16 rows (p, p+16) in one u32):
//   byte(pair p, col) = (col<<6) ^ (((col>>1)&3)<<4) ^ (p<<2)
// One ds_read_b32 = A-frag element (row n) for BOTH 16-row tiles.
// 1024 threads = 16 waves, wave w owns group w (2 blocks/CU -> 32 waves/CU cap).

extern "C" __global__ __launch_bounds__(1024, 8)
void denc_kernel(const float* __restrict__ x,
                 const int* __restrict__ a1, const float* __restrict__ b1,
                 const int* __restrict__ a2, const float* __restrict__ b2,
                 const int* __restrict__ a3, const float* __restrict__ b3,
                 const int* __restrict__ a4, const float* __restrict__ b4,
                 const uint32_t* __restrict__ kt,
                 float* __restrict__ out)
{
    __shared__ int4 ftile[4096];                     // 64 KB
    const char* tfc = (const char*)ftile;

    const int tid  = threadIdx.x;
    const int w    = tid >> 6;                       // wave = group 0..15
    const int lane = tid & 63;
    const int q    = lane >> 4;                      // k-block / D row-quad
    const int n    = lane & 15;                      // A row-pair / B,D col
    const int R0   = blockIdx.x * RPB;
    const int Ln   = n << 2;                         // lane part of gather addr

    // ---- stage x: thread covers col c=tid&255, pair-quad j=tid>>8 ----
    {
        const int c = tid & 255;
        const int j = tid >> 8;                      // 0..3 -> pairs 4j..4j+3
        const float* xb = x + (size_t)R0 * 256 + c;
        uint32_t qp[4];
        #pragma unroll
        for (int k = 0; k < 4; ++k) {
            const int p = j * 4 + k;
            qp[k] = pkrtz(xb[(size_t)p * 256], xb[(size_t)(p + 16) * 256]);
        }
        const int s = (c >> 1) & 3;
        ftile[c * 4 + (j ^ s)] = make_int4((int)qp[0], (int)qp[1], (int)qp[2], (int)qp[3]);
    }

    // prefetch level-1 gather addresses (hides L2 latency behind the barrier)
    int4 pa = *(const int4*)(a1 + w * 32 + q * 8);
    int4 pb = *(const int4*)(a1 + w * 32 + q * 8 + 4);

#define LEVEL(ApNext, Bp, LVLBASE, OB, LAST) do { \
    __syncthreads(); \
    const uint32_t r0 = *(const uint32_t*)(tfc + (pa.x ^ Ln)); \
    const uint32_t r1 = *(const uint32_t*)(tfc + (pa.y ^ Ln)); \
    const uint32_t r2 = *(const uint32_t*)(tfc + (pa.z ^ Ln)); \
    const uint32_t r3 = *(const uint32_t*)(tfc + (pa.w ^ Ln)); \
    const uint32_t r4 = *(const uint32_t*)(tfc + (pb.x ^ Ln)); \
    const uint32_t r5 = *(const uint32_t*)(tfc + (pb.y ^ Ln)); \
    const uint32_t r6 = *(const uint32_t*)(tfc + (pb.z ^ Ln)); \
    const uint32_t r7 = *(const uint32_t*)(tfc + (pb.w ^ Ln)); \
    if (!(LAST)) {                                   /* prefetch next level */ \
        pa = *(const int4*)((ApNext) + w * 32 + q * 8); \
        pb = *(const int4*)((ApNext) + w * 32 + q * 8 + 4); \
    } \
    const u32x4 bf = *(const u32x4*)(kt + (size_t)((LVLBASE) + w * 64 + q * 16 + n) * 4); \
    const float bvv = (Bp)[w * 16 + n]; \
    f32x4 accA = {bvv, bvv, bvv, bvv}, accB = accA; \
    u32x4 fA, fB; \
    fA.x = __builtin_amdgcn_perm(r1, r0, SEL_LO); fB.x = __builtin_amdgcn_perm(r1, r0, SEL_HI); \
    fA.y = __builtin_amdgcn_perm(r3, r2, SEL_LO); fB.y = __builtin_amdgcn_perm(r3, r2, SEL_HI); \
    fA.z = __builtin_amdgcn_perm(r5, r4, SEL_LO); fB.z = __builtin_amdgcn_perm(r5, r4, SEL_HI); \
    fA.w = __builtin_amdgcn_perm(r7, r6, SEL_LO); fB.w = __builtin_amdgcn_perm(r7, r6, SEL_HI); \
    accA = __builtin_amdgcn_mfma_f32_16x16x32_f16( \
        __builtin_bit_cast(half8, fA), __builtin_bit_cast(half8, bf), accA, 0, 0, 0); \
    accB = __builtin_amdgcn_mfma_f32_16x16x32_f16( \
        __builtin_bit_cast(half8, fB), __builtin_bit_cast(half8, bf), accB, 0, 0, 0); \
    const float tA0 = fast_tanh(accA[0]), tA1 = fast_tanh(accA[1]); \
    const float tA2 = fast_tanh(accA[2]), tA3 = fast_tanh(accA[3]); \
    const float tB0 = fast_tanh(accB[0]), tB1 = fast_tanh(accB[1]); \
    const float tB2 = fast_tanh(accB[2]), tB3 = fast_tanh(accB[3]); \
    if (LAST) { \
        float* ob = out + (size_t)(R0 + q * 4) * 256 + w * 16 + n; \
        ob[0]    = tA0; ob[256]  = tA1; ob[512]  = tA2; ob[768]  = tA3; \
        ob[4096] = tB0; ob[4352] = tB1; ob[4608] = tB2; ob[4864] = tB3; \
    } else { \
        const int col = (OB) + w * 16 + n; \
        const int s = (col >> 1) & 3; \
        ftile[col * 4 + (q ^ s)] = make_int4( \
            (int)pkrtz(tA0, tB0), (int)pkrtz(tA1, tB1), \
            (int)pkrtz(tA2, tB2), (int)pkrtz(tA3, tB3)); \
    } \
} while (0)

    LEVEL(a2, b1,    0, NIN,       0);
    LEVEL(a3, b2, 1024, NIN + 256, 0);
    LEVEL(a4, b3, 2048, NIN + 512, 0);
    LEVEL(a4, b4, 3072, 0,         1);

#undef LEVEL
}

extern "C" void kernel_launch(void* const* d_in, const int* in_sizes, int n_in,
                              void* d_out, int out_size, void* d_ws, size_t ws_size,
                              hipStream_t stream) {
    const float* x  = (const float*)d_in[0];
    const float* k1 = (const float*)d_in[1];
    const float* b1 = (const float*)d_in[2];
    const int*   i1 = (const int*)  d_in[3];
    const float* k2 = (const float*)d_in[4];
    const float* b2 = (const float*)d_in[5];
    const int*   i2 = (const int*)  d_in[6];
    const float* k3 = (const float*)d_in[7];
    const float* b3 = (const float*)d_in[8];
    const int*   i3 = (const int*)  d_in[9];
    const float* k4 = (const float*)d_in[10];
    const float* b4 = (const float*)d_in[11];
    const int*   i4 = (const int*)  d_in[12];
    float* out = (float*)d_out;
    uint32_t* kt = (uint32_t*)d_ws;                  // 64 KB
    int* apre = (int*)((char*)d_ws + 65536);         // 8 KB

    hipLaunchKernelGGL(kprep_kernel, dim3(16), dim3(256), 0, stream,
                       k1, k2, k3, k4, i1, i2, i3, i4, kt, apre);

    const int batch = in_sizes[0] / NIN;             // 65536
    hipLaunchKernelGGL(denc_kernel, dim3(batch / RPB), dim3(1024), 0, stream,
                       x, apre, b1, apre + 512, b2, apre + 1024, b3, apre + 1536, b4,
                       (const uint32_t*)kt, out);
}